// Round 4
// baseline (188.236 us; speedup 1.0000x reference)
//
#include <hip/hip_runtime.h>
#include <hip/hip_bf16.h>
#include <stdint.h>
#include <stddef.h>

typedef __attribute__((ext_vector_type(4))) float f32x4;
typedef __attribute__((ext_vector_type(8))) short s16x8;

#define B_    8
#define L_    8192
#define N_    256
#define DOUT_ 256

__device__ __forceinline__ unsigned short f2bf(float f) {
  unsigned int x = __float_as_uint(f);
  x += 0x7fff + ((x >> 16) & 1);   // RNE
  return (unsigned short)(x >> 16);
}

// ---- kernel 0: zero upper half of out (rows 4096..8191 per batch) — atomicAdd region ----
__global__ void k_zero(float* __restrict__ out) {
  int t = blockIdx.x * 256 + threadIdx.x;        // 2,097,152 threads
  int b = t >> 18;                               // 262144 f32x4 per batch
  int r = t & 262143;
  f32x4 z = {0.f, 0.f, 0.f, 0.f};
  *(f32x4*)(out + (size_t)b * 2097152 + 1048576 + (size_t)r * 4) = z;
}

// ---- kernel 1: urev[b][j] = j<=8191 ? bf16(u[b][8191-j]) : 0   (zero-padded reversed u) ----
__global__ void k_urev(const float* __restrict__ u, unsigned short* __restrict__ urev) {
  int t = blockIdx.x * 256 + threadIdx.x;        // 131072 threads
  int b = t >> 14;
  int j = t & 16383;
  unsigned short v = 0;
  if (j <= 8191) v = f2bf(u[b * L_ + 8191 - j]);
  urev[t] = v;
}

// ---- kernel 2: Amat[b][d][l'][i'] (65 d-slots; slot 64 = zeros), branch-free from urev ----
__global__ void k_amat(const unsigned short* __restrict__ urev, unsigned short* __restrict__ Am) {
  int t = blockIdx.x * 256 + threadIdx.x;   // 4160*256 = 8*65*128*16 threads
  int i0 = (t & 15) * 8;
  int lp = (t >> 4) & 127;
  int r2 = t >> 11;           // b*65 + d
  int d  = r2 % 65;
  int b  = r2 / 65;
  s16x8 v;
#pragma unroll
  for (int j = 0; j < 8; ++j) v[j] = 0;
  if (d < 64) {
    const unsigned short* ur = urev + b * 16384;
    int jbase = 8191 - 128 * d - lp + i0;   // in [0, 8311]; urev pads zeros past 8191
#pragma unroll
    for (int j = 0; j < 8; ++j) v[j] = (short)ur[jbase + j];
  }
  *(s16x8*)(Am + (size_t)t * 8) = v;
}

// ---- kernel 3: gT[o][i] = sum_n W[o][n] * h[i][n], inline f32->bf16 convert ----
__global__ void k_gt(const float* __restrict__ W, const float* __restrict__ h,
                     unsigned short* __restrict__ gT) {
  int gid  = blockIdx.x * 256 + threadIdx.x;
  int lane = gid & 63;
  int wid  = gid >> 6;        // 0..2047
  int o_t  = wid >> 7;        // 0..15
  int i_t  = wid & 127;       // 0..127
  int o0 = o_t * 16, i0 = i_t * 64;
  int ln = lane & 15, hi = lane >> 4;
  f32x4 acc[4] = {};
#pragma unroll
  for (int k0 = 0; k0 < N_; k0 += 32) {
    const float* wp = W + (o0 + ln) * N_ + k0 + 8 * hi;
    float4 w0 = *(const float4*)wp;
    float4 w1 = *(const float4*)(wp + 4);
    s16x8 a;
    a[0] = (short)f2bf(w0.x); a[1] = (short)f2bf(w0.y);
    a[2] = (short)f2bf(w0.z); a[3] = (short)f2bf(w0.w);
    a[4] = (short)f2bf(w1.x); a[5] = (short)f2bf(w1.y);
    a[6] = (short)f2bf(w1.z); a[7] = (short)f2bf(w1.w);
#pragma unroll
    for (int ns = 0; ns < 4; ++ns) {
      const float* hp = h + (size_t)(i0 + 16 * ns + ln) * N_ + k0 + 8 * hi;
      float4 h0 = *(const float4*)hp;
      float4 h1 = *(const float4*)(hp + 4);
      s16x8 bb;
      bb[0] = (short)f2bf(h0.x); bb[1] = (short)f2bf(h0.y);
      bb[2] = (short)f2bf(h0.z); bb[3] = (short)f2bf(h0.w);
      bb[4] = (short)f2bf(h1.x); bb[5] = (short)f2bf(h1.y);
      bb[6] = (short)f2bf(h1.z); bb[7] = (short)f2bf(h1.w);
      acc[ns] = __builtin_amdgcn_mfma_f32_16x16x32_bf16(a, bb, acc[ns], 0, 0, 0);
    }
  }
#pragma unroll
  for (int ns = 0; ns < 4; ++ns)
#pragma unroll
    for (int q = 0; q < 4; ++q)
      gT[(size_t)(o0 + 4 * hi + q) * L_ + i0 + 16 * ns + ln] = f2bf(acc[ns][q]);
}

// ---------------- kernel 4: main Toeplitz GEMM ----------------
// BM=256 BN=256 BK=64, 8 waves (2M x 4N, per-wave 128x64). 2-deep LDS dbuf,
// XOR slot-swizzle both sides. 256 balanced blocks: each pair (Rb=31-zp, Rs=zp)
// = 132 K-steps split into halves of 66. Upper-half output tiles (R>=16) are
// written by BOTH halves -> atomicAdd onto zeroed out; small tiles plain store.
__global__ __launch_bounds__(512, 2) void k_main(const unsigned short* __restrict__ Am,
                                                 const unsigned short* __restrict__ gT,
                                                 float* __restrict__ out) {
  __shared__ short As[2][16384];   // [buf][256 rows][64 k] swizzled, 64 KB
  __shared__ short Bs[2][16384];   // [buf][256 rows][64 k] swizzled, 64 KB
  const int half = blockIdx.x;       // 0,1
  const int b    = blockIdx.y;       // 0..7
  const int zp   = blockIdx.z;       // 0..15
  const int Rb = 31 - zp, Rs = zp;
  const int nktb = 4 * (Rb + 1);     // 68..128
  const int s_lo = half ? 66 : 0;
  const int s_hi = half ? 132 : 66;
  const int tid = threadIdx.x;
  const int lane = tid & 63;
  const int w = tid >> 6;
  const int wr = w >> 2, wc = w & 3;           // 2M x 4N
  const int ln = lane & 15, hi = lane >> 4;

  // staging precompute: thread owns chunk (row = tid>>3 (+64q), phys slot = tid&7)
  const int t3 = tid >> 3;
  const int sA = ((tid & 7) ^ (t3 & 7)) << 3;  // XOR-swizzled logical slot (shorts)
  const unsigned short* AmB = Am + (size_t)(b * 65) * 16384;
  const unsigned short* Bq[4] = {
    gT + (size_t)(t3)       * L_ + sA,
    gT + (size_t)(t3 + 64)  * L_ + sA,
    gT + (size_t)(t3 + 128) * L_ + sA,
    gT + (size_t)(t3 + 192) * L_ + sA };
  const int rl0 = t3, rl1 = 64 + t3;

  // fragment-read precompute (swizzled ds_read addresses, shorts)
  const int offA = (wr * 128 + ln) * 64;
  const int offB = (wc * 64 + ln) * 64;
  const int sw = ln & 7;
  const int k0o = (hi ^ sw) * 8;
  const int k1o = ((hi + 4) ^ sw) * 8;

  float* outb = out + (size_t)b * (L_ * DOUT_);
  f32x4 acc[8][4] = {};

#define ISSUE_A(Rv, ktv, dst, q) do { \
    int dd = 2 * (Rv) + ((q) >> 1) - ((ktv) >> 1); \
    int sd = dd < 0 ? 64 : dd; \
    const unsigned short* src = AmB + ((size_t)sd << 14) + (((q) & 1 ? rl1 : rl0) << 7) + (((ktv) & 1) << 6) + sA; \
    __builtin_amdgcn_global_load_lds((const __attribute__((address_space(1))) void*)src, \
        (__attribute__((address_space(3))) void*)((dst) + (tid + 512 * (q)) * 8), 16, 0, 0); \
  } while (0)

#define ISSUE_B(ktv, dst, q) do { \
    const unsigned short* src = Bq[q] + (ktv) * 64; \
    __builtin_amdgcn_global_load_lds((const __attribute__((address_space(1))) void*)src, \
        (__attribute__((address_space(3))) void*)((dst) + (tid + 512 * (q)) * 8), 16, 0, 0); \
  } while (0)

  auto flush = [&](int R, bool atomic) {
    const int l0 = R * 256 + wr * 128 + 4 * hi;
    const int o0 = wc * 64 + ln;
#pragma unroll
    for (int m = 0; m < 8; ++m)
#pragma unroll
      for (int q = 0; q < 4; ++q) {
        float* rowp = outb + (size_t)(l0 + m * 16 + q) * DOUT_ + o0;
#pragma unroll
        for (int n = 0; n < 4; ++n) {
          if (atomic) atomicAdd(rowp + n * 16, acc[m][n][q]);
          else        rowp[n * 16] = acc[m][n][q];
        }
      }
#pragma unroll
    for (int m = 0; m < 8; ++m)
#pragma unroll
      for (int n = 0; n < 4; ++n)
        acc[m][n] = (f32x4){0.f, 0.f, 0.f, 0.f};
  };

  // prologue: stage step s_lo (s_lo < nktb always, since nktb >= 68)
  {
    short* Aw = &As[s_lo & 1][0];
    short* Bw = &Bs[s_lo & 1][0];
    const int kt0 = s_lo;   // s_lo is in section Rb
    ISSUE_A(Rb, kt0, Aw, 0); ISSUE_A(Rb, kt0, Aw, 1);
    ISSUE_A(Rb, kt0, Aw, 2); ISSUE_A(Rb, kt0, Aw, 3);
    ISSUE_B(kt0, Bw, 0); ISSUE_B(kt0, Bw, 1);
    ISSUE_B(kt0, Bw, 2); ISSUE_B(kt0, Bw, 3);
  }

  for (int s = s_lo; s < s_hi; ++s) {
    // tile-s loads were issued a full K-tile ago -> vmcnt(0) is ~free
    asm volatile("s_waitcnt vmcnt(0)" ::: "memory");
    __builtin_amdgcn_sched_barrier(0);
    __builtin_amdgcn_s_barrier();
    __builtin_amdgcn_sched_barrier(0);

    if (half && s == nktb) flush(Rb, true);   // section boundary: emit big tile

    const short* Ac = &As[s & 1][0];
    const short* Bc = &Bs[s & 1][0];
    short* Aw = &As[(s + 1) & 1][0];
    short* Bw = &Bs[(s + 1) & 1][0];
    const int s1  = (s + 1 < s_hi) ? s + 1 : s;     // clamp keeps issue count uniform
    const int R1  = (s1 < nktb) ? Rb : Rs;
    const int kt1 = (s1 < nktb) ? s1 : s1 - nktb;

    s16x8 bf[4], af[4];
    // ---------------- kk = 0 ----------------
#pragma unroll
    for (int n = 0; n < 4; ++n) bf[n] = *(const s16x8*)(Bc + offB + n * 1024 + k0o);
    ISSUE_A(R1, kt1, Aw, 0); ISSUE_A(R1, kt1, Aw, 1);
#pragma unroll
    for (int m = 0; m < 4; ++m) af[m] = *(const s16x8*)(Ac + offA + m * 1024 + k0o);
    __builtin_amdgcn_s_setprio(1);
#pragma unroll
    for (int m = 0; m < 4; ++m)
#pragma unroll
      for (int n = 0; n < 4; ++n)
        acc[m][n] = __builtin_amdgcn_mfma_f32_16x16x32_bf16(af[m], bf[n], acc[m][n], 0, 0, 0);
    __builtin_amdgcn_s_setprio(0);
    ISSUE_A(R1, kt1, Aw, 2); ISSUE_A(R1, kt1, Aw, 3);
#pragma unroll
    for (int m = 0; m < 4; ++m) af[m] = *(const s16x8*)(Ac + offA + 4096 + m * 1024 + k0o);
    __builtin_amdgcn_s_setprio(1);
#pragma unroll
    for (int m = 0; m < 4; ++m)
#pragma unroll
      for (int n = 0; n < 4; ++n)
        acc[4 + m][n] = __builtin_amdgcn_mfma_f32_16x16x32_bf16(af[m], bf[n], acc[4 + m][n], 0, 0, 0);
    __builtin_amdgcn_s_setprio(0);
    // ---------------- kk = 1 ----------------
#pragma unroll
    for (int n = 0; n < 4; ++n) bf[n] = *(const s16x8*)(Bc + offB + n * 1024 + k1o);
    ISSUE_B(kt1, Bw, 0); ISSUE_B(kt1, Bw, 1);
#pragma unroll
    for (int m = 0; m < 4; ++m) af[m] = *(const s16x8*)(Ac + offA + m * 1024 + k1o);
    __builtin_amdgcn_s_setprio(1);
#pragma unroll
    for (int m = 0; m < 4; ++m)
#pragma unroll
      for (int n = 0; n < 4; ++n)
        acc[m][n] = __builtin_amdgcn_mfma_f32_16x16x32_bf16(af[m], bf[n], acc[m][n], 0, 0, 0);
    __builtin_amdgcn_s_setprio(0);
    ISSUE_B(kt1, Bw, 2); ISSUE_B(kt1, Bw, 3);
#pragma unroll
    for (int m = 0; m < 4; ++m) af[m] = *(const s16x8*)(Ac + offA + 4096 + m * 1024 + k1o);
    __builtin_amdgcn_s_setprio(1);
#pragma unroll
    for (int m = 0; m < 4; ++m)
#pragma unroll
      for (int n = 0; n < 4; ++n)
        acc[4 + m][n] = __builtin_amdgcn_mfma_f32_16x16x32_bf16(af[m], bf[n], acc[4 + m][n], 0, 0, 0);
    __builtin_amdgcn_s_setprio(0);
  }

  // drain dummy prefetches' in-flight LDS writes before teardown
  asm volatile("s_waitcnt vmcnt(0)" ::: "memory");

  if (half) flush(Rs, false);   // small tile: written only by half 1 -> plain store
  else      flush(Rb, true);    // big tile partial -> atomicAdd

#undef ISSUE_A
#undef ISSUE_B
}

extern "C" void kernel_launch(void* const* d_in, const int* in_sizes, int n_in,
                              void* d_out, int out_size, void* d_ws, size_t ws_size,
                              hipStream_t stream) {
  const float* u = (const float*)d_in[0];   // [8, 8192, 1]
  const float* h = (const float*)d_in[1];   // [8192, 256]
  const float* W = (const float*)d_in[2];   // [256, 256]
  float* out = (float*)d_out;               // [8, 8192, 256]

  char* ws = (char*)d_ws;
  const size_t AM_BYTES = (size_t)8 * 65 * 16384 * 2;     // 17,039,360
  unsigned short* Am   = (unsigned short*)ws;
  unsigned short* gT   = (unsigned short*)(ws + AM_BYTES);               // 4 MB
  unsigned short* urev = (unsigned short*)(ws + AM_BYTES + (size_t)4 * 1024 * 1024); // 256 KB

  k_zero<<<8192, 256, 0, stream>>>(out);
  k_urev<<<512, 256, 0, stream>>>(u, urev);
  k_amat<<<4160, 256, 0, stream>>>(urev, Am);
  k_gt<<<512, 256, 0, stream>>>(W, h, gT);
  k_main<<<dim3(2, 8, 16), 512, 0, stream>>>(Am, gT, out);
}